// Round 1
// baseline (3038.563 us; speedup 1.0000x reference)
//
#include <hip/hip_runtime.h>

#define NN 64
#define LD 68     // 64 + 4 pad (keeps float4 alignment, breaks pow2 strides)
#define MM 32
#define LD2 36

__device__ __forceinline__ float4 ld4(const float* p) {
  return *reinterpret_cast<const float4*>(p);
}
__device__ __forceinline__ void st4(float* p, float4 v) {
  *reinterpret_cast<float4*>(p) = v;
}

// T = 1.5*I - 0.5*(Z^T Y)  (Z symmetric => == Z*Y). Tb distinct from Zb,Yb.
__device__ __forceinline__ void mm_nsT(const float* __restrict__ Zb,
                                       const float* __restrict__ Yb,
                                       float* __restrict__ Tb, int r, int c) {
  float acc[4][4];
#pragma unroll
  for (int i = 0; i < 4; ++i)
#pragma unroll
    for (int j = 0; j < 4; ++j) acc[i][j] = 0.f;
#pragma unroll 4
  for (int k = 0; k < NN; ++k) {
    float4 a = ld4(&Zb[k * LD + r]);
    float4 b = ld4(&Yb[k * LD + c]);
    float av[4] = {a.x, a.y, a.z, a.w};
    float bv[4] = {b.x, b.y, b.z, b.w};
#pragma unroll
    for (int i = 0; i < 4; ++i)
#pragma unroll
      for (int j = 0; j < 4; ++j) acc[i][j] = fmaf(av[i], bv[j], acc[i][j]);
  }
#pragma unroll
  for (int i = 0; i < 4; ++i) {
    float4 w;
    w.x = ((r + i) == (c + 0) ? 1.5f : 0.f) - 0.5f * acc[i][0];
    w.y = ((r + i) == (c + 1) ? 1.5f : 0.f) - 0.5f * acc[i][1];
    w.z = ((r + i) == (c + 2) ? 1.5f : 0.f) - 0.5f * acc[i][2];
    w.w = ((r + i) == (c + 3) ? 1.5f : 0.f) - 0.5f * acc[i][3];
    st4(&Tb[(r + i) * LD + c], w);
  }
  __syncthreads();
}

// Y <- Y*T ; Z <- T*Z   (all symmetric; in-place with register staging)
__device__ __forceinline__ void mm_nsUpd(float* __restrict__ Yb,
                                         float* __restrict__ Zb,
                                         const float* __restrict__ Tb,
                                         int r, int c) {
  float accY[4][4], accZ[4][4];
#pragma unroll
  for (int i = 0; i < 4; ++i)
#pragma unroll
    for (int j = 0; j < 4; ++j) { accY[i][j] = 0.f; accZ[i][j] = 0.f; }
#pragma unroll 2
  for (int k = 0; k < NN; ++k) {
    float4 yr = ld4(&Yb[k * LD + r]);
    float4 tc = ld4(&Tb[k * LD + c]);
    float4 tr = ld4(&Tb[k * LD + r]);
    float4 zc = ld4(&Zb[k * LD + c]);
    float yv[4] = {yr.x, yr.y, yr.z, yr.w};
    float tcv[4] = {tc.x, tc.y, tc.z, tc.w};
    float trv[4] = {tr.x, tr.y, tr.z, tr.w};
    float zv[4] = {zc.x, zc.y, zc.z, zc.w};
#pragma unroll
    for (int i = 0; i < 4; ++i)
#pragma unroll
      for (int j = 0; j < 4; ++j) {
        accY[i][j] = fmaf(yv[i], tcv[j], accY[i][j]);  // Y'[r+i][c+j]
        accZ[i][j] = fmaf(trv[i], zv[j], accZ[i][j]);  // Z'[r+i][c+j]
      }
  }
  __syncthreads();  // all reads of Y,Z done before overwrite
#pragma unroll
  for (int i = 0; i < 4; ++i) {
    float4 wy, wz;
    wy.x = accY[i][0]; wy.y = accY[i][1]; wy.z = accY[i][2]; wy.w = accY[i][3];
    wz.x = accZ[i][0]; wz.y = accZ[i][1]; wz.z = accZ[i][2]; wz.w = accZ[i][3];
    st4(&Yb[(r + i) * LD + c], wy);
    st4(&Zb[(r + i) * LD + c], wz);
  }
  __syncthreads();
}

// Cb = alpha*(A^T B) + cdiag*I. Cb distinct from Ab,Bb.
__device__ __forceinline__ void mm_axbI(const float* __restrict__ Ab,
                                        const float* __restrict__ Bb,
                                        float* __restrict__ Cb,
                                        float alpha, float cdiag, int r, int c) {
  float acc[4][4];
#pragma unroll
  for (int i = 0; i < 4; ++i)
#pragma unroll
    for (int j = 0; j < 4; ++j) acc[i][j] = 0.f;
#pragma unroll 4
  for (int k = 0; k < NN; ++k) {
    float4 a = ld4(&Ab[k * LD + r]);
    float4 b = ld4(&Bb[k * LD + c]);
    float av[4] = {a.x, a.y, a.z, a.w};
    float bv[4] = {b.x, b.y, b.z, b.w};
#pragma unroll
    for (int i = 0; i < 4; ++i)
#pragma unroll
      for (int j = 0; j < 4; ++j) acc[i][j] = fmaf(av[i], bv[j], acc[i][j]);
  }
#pragma unroll
  for (int i = 0; i < 4; ++i) {
    float4 w;
    w.x = alpha * acc[i][0] + ((r + i) == (c + 0) ? cdiag : 0.f);
    w.y = alpha * acc[i][1] + ((r + i) == (c + 1) ? cdiag : 0.f);
    w.z = alpha * acc[i][2] + ((r + i) == (c + 2) ? cdiag : 0.f);
    w.w = alpha * acc[i][3] + ((r + i) == (c + 3) ? cdiag : 0.f);
    st4(&Cb[(r + i) * LD + c], w);
  }
  __syncthreads();
}

// 32x32: Cb = (P^T Q) + cdiag*I  (P symmetric). Each thread: 1 row x 4 cols.
__device__ __forceinline__ void mm32(const float* __restrict__ Pb,
                                     const float* __restrict__ Qb,
                                     float* __restrict__ Cb,
                                     float cdiag, int row, int c4) {
  float a0 = 0.f, a1 = 0.f, a2 = 0.f, a3 = 0.f;
#pragma unroll 4
  for (int k = 0; k < MM; ++k) {
    float a = Pb[k * LD2 + row];
    float4 b = ld4(&Qb[k * LD2 + c4]);
    a0 = fmaf(a, b.x, a0);
    a1 = fmaf(a, b.y, a1);
    a2 = fmaf(a, b.z, a2);
    a3 = fmaf(a, b.w, a3);
  }
  float4 w;
  w.x = a0 + ((row == c4 + 0) ? cdiag : 0.f);
  w.y = a1 + ((row == c4 + 1) ? cdiag : 0.f);
  w.z = a2 + ((row == c4 + 2) ? cdiag : 0.f);
  w.w = a3 + ((row == c4 + 3) ? cdiag : 0.f);
  st4(&Cb[row * LD2 + c4], w);
  __syncthreads();
}

__global__ void __launch_bounds__(256)
spd_pool_kernel(const float* __restrict__ X, float* __restrict__ out) {
  __shared__ __align__(16) float bY[NN * LD];
  __shared__ __align__(16) float bZ[NN * LD];
  __shared__ __align__(16) float bT[NN * LD];

  const int tid = threadIdx.x;
  const int tx = tid & 15, ty = tid >> 4;
  const int r = ty * 4, c = tx * 4;
  const float* Xg = X + (size_t)blockIdx.x * (NN * NN);

  // ---- Level-1 Newton-Schulz sqrt of X/c1 (c1=2.2; spectrum [0.45,2.64]) ----
  const float inv_c1 = 1.0f / 2.2f;
#pragma unroll
  for (int m = 0; m < 16; ++m) {
    int idx = tid + 256 * m;
    int row = idx >> 6, col = idx & 63;
    bY[row * LD + col] = Xg[idx] * inv_c1;
    bZ[row * LD + col] = (row == col) ? 1.f : 0.f;
  }
  __syncthreads();

  for (int it = 0; it < 9; ++it) {
    mm_nsT(bZ, bY, bT, r, c);
    mm_nsUpd(bY, bZ, bT, r, c);
  }

  // ---- Level-2: Y2_0 = X^{1/2}/c2 = Y * sqrt(c1)/c2 (c2=1.6) ----
  const float s12 = 0.92702481f;  // sqrt(2.2)/1.6
#pragma unroll
  for (int m = 0; m < 16; ++m) {
    int idx = tid + 256 * m;
    int row = idx >> 6, col = idx & 63;
    bY[row * LD + col] *= s12;
    bZ[row * LD + col] = (row == col) ? 1.f : 0.f;
  }
  __syncthreads();

  for (int it = 0; it < 5; ++it) {
    mm_nsT(bZ, bY, bT, r, c);
    mm_nsUpd(bY, bZ, bT, r, c);
  }

  // ---- E = sqrt(c2)*Y - I  -> bT  (spectrum [0, 0.56]) ----
  const float s2 = 1.26491106f;  // sqrt(1.6)
#pragma unroll
  for (int m = 0; m < 16; ++m) {
    int idx = tid + 256 * m;
    int row = idx >> 6, col = idx & 63;
    bT[row * LD + col] = s2 * bY[row * LD + col] - ((row == col) ? 1.f : 0.f);
  }
  __syncthreads();

  // ---- log(I+E), degree-16 Taylor, Horner. q init = c16*E + c15*I -> bZ ----
#pragma unroll
  for (int m = 0; m < 16; ++m) {
    int idx = tid + 256 * m;
    int row = idx >> 6, col = idx & 63;
    bZ[row * LD + col] =
        (-1.f / 16.f) * bT[row * LD + col] + ((row == col) ? (1.f / 15.f) : 0.f);
  }
  __syncthreads();

  float* q = bZ;
  float* qo = bY;
  for (int j = 14; j >= 1; --j) {
    float coef = ((j & 1) ? 1.f : -1.f) / (float)j;
    mm_axbI(bT, q, qo, 1.f, coef, r, c);
    float* t = q; q = qo; qo = t;
  }
  // 14 swaps (even) -> q == bZ, qo == bY.  L = 4 * E * q -> bY
  mm_axbI(bT, q, qo, 4.f, 0.f, r, c);
  float* L = qo;  // bY

  // ---- pool 2x2 + symmetrize -> P (32x32, stride LD2) in bZ region ----
  float* P = bZ;
#pragma unroll
  for (int m = 0; m < 4; ++m) {
    int e = tid + 256 * m;
    int i = e >> 5, j = e & 31;
    float s = L[(2 * i) * LD + 2 * j] + L[(2 * i) * LD + 2 * j + 1] +
              L[(2 * i + 1) * LD + 2 * j] + L[(2 * i + 1) * LD + 2 * j + 1] +
              L[(2 * j) * LD + 2 * i] + L[(2 * j) * LD + 2 * i + 1] +
              L[(2 * j + 1) * LD + 2 * i] + L[(2 * j + 1) * LD + 2 * i + 1];
    P[i * LD2 + j] = 0.125f * s;
  }
  __syncthreads();

  // ---- exp(P), degree-12 Taylor (||P|| <= ~0.88), Horner on 32x32 ----
  const float dfac[13] = {1.f,
                          1.f,
                          0.5f,
                          1.f / 6.f,
                          1.f / 24.f,
                          1.f / 120.f,
                          1.f / 720.f,
                          1.f / 5040.f,
                          1.f / 40320.f,
                          1.f / 362880.f,
                          1.f / 3628800.f,
                          1.f / 39916800.f,
                          1.f / 479001600.f};

  float* q2 = bT;   // 32x36 region carved from bT
  float* q2o = bY;  // 32x36 region carved from bY (L consumed)
#pragma unroll
  for (int m = 0; m < 4; ++m) {
    int e = tid + 256 * m;
    int i = e >> 5, j = e & 31;
    q2[i * LD2 + j] = dfac[12] * P[i * LD2 + j] + ((i == j) ? dfac[11] : 0.f);
  }
  __syncthreads();

  const int row32 = tid >> 3;
  const int c432 = (tid & 7) * 4;
  for (int j = 10; j >= 0; --j) {
    mm32(P, q2, q2o, dfac[j], row32, c432);
    float* t = q2; q2 = q2o; q2o = t;
  }
  // result in q2

  float4 w = ld4(&q2[row32 * LD2 + c432]);
  st4(&out[(size_t)blockIdx.x * 1024 + 4 * tid], w);
}

extern "C" void kernel_launch(void* const* d_in, const int* in_sizes, int n_in,
                              void* d_out, int out_size, void* d_ws, size_t ws_size,
                              hipStream_t stream) {
  const float* X = (const float*)d_in[0];
  float* out = (float*)d_out;
  const int batch = in_sizes[0] / (NN * NN);  // 8192
  spd_pool_kernel<<<batch, 256, 0, stream>>>(X, out);
}

// Round 2
// 1053.566 us; speedup vs baseline: 2.8841x; 2.8841x over previous
//
#include <hip/hip_runtime.h>

typedef __attribute__((ext_vector_type(8))) short short8;
typedef __attribute__((ext_vector_type(4))) short short4v;
typedef __attribute__((ext_vector_type(16))) float f32x16;

#define PL 8192  // lo-plane offset within a slot (each plane 64*128B = 8KB)

// swizzled byte address inside a plane: row m (0..63), 16B chunk kc (0..7)
__device__ __forceinline__ int swadr(int m, int kc) {
  return m * 128 + (((kc) ^ (m & 7)) << 4);
}

__device__ __forceinline__ f32x16 zero16() {
  f32x16 z;
#pragma unroll
  for (int i = 0; i < 16; ++i) z[i] = 0.f;
  return z;
}

// split v[8] into bf16 hi/lo planes, 16B store each (truncation split)
__device__ __forceinline__ void split_store8(char* slot, int byteoff, const float* v) {
  short8 h, l;
#pragma unroll
  for (int i = 0; i < 8; ++i) {
    unsigned int u = __float_as_uint(v[i]);
    h[i] = (short)(u >> 16);
    float hf = __uint_as_float(u & 0xFFFF0000u);
    float lo = v[i] - hf;
    l[i] = (short)(__float_as_uint(lo) >> 16);
  }
  *(short8*)(slot + byteoff) = h;
  *(short8*)(slot + PL + byteoff) = l;
}

__device__ __forceinline__ void split_store4(char* slot, int byteoff, const float* v) {
  short4v h, l;
#pragma unroll
  for (int i = 0; i < 4; ++i) {
    unsigned int u = __float_as_uint(v[i]);
    h[i] = (short)(u >> 16);
    float hf = __uint_as_float(u & 0xFFFF0000u);
    float lo = v[i] - hf;
    l[i] = (short)(__float_as_uint(lo) >> 16);
  }
  *(short4v*)(slot + byteoff) = h;
  *(short4v*)(slot + PL + byteoff) = l;
}

// compose 8 fp32 from hi/lo planes at a 16B chunk
__device__ __forceinline__ void load_compose8(const char* slot, int byteoff, float* v) {
  short8 h = *(const short8*)(slot + byteoff);
  short8 l = *(const short8*)(slot + PL + byteoff);
#pragma unroll
  for (int i = 0; i < 8; ++i) {
    unsigned int uh = ((unsigned int)(unsigned short)h[i]) << 16;
    unsigned int ul = ((unsigned int)(unsigned short)l[i]) << 16;
    v[i] = __uint_as_float(uh) + __uint_as_float(ul);
  }
}

// acc += A*B tile (32x32), A rows mA.., B rows mB.. (B symmetric => row-read),
// 2-term split: Ah*Bh + Ah*Bl + Al*Bh.  NK = number of 16-wide k-steps.
template <int NK>
__device__ __forceinline__ void mac_tile(f32x16& acc, const char* A, const char* B,
                                         int mA, int mB, int half) {
  const int baseA = mA * 128, maskA = mA & 7;
  const int baseB = mB * 128, maskB = mB & 7;
#pragma unroll
  for (int s = 0; s < NK; ++s) {
    const int kc = 2 * s + half;
    const int oA = baseA + ((kc ^ maskA) << 4);
    const int oB = baseB + ((kc ^ maskB) << 4);
    short8 ah = *(const short8*)(A + oA);
    short8 al = *(const short8*)(A + PL + oA);
    short8 bh = *(const short8*)(B + oB);
    short8 bl = *(const short8*)(B + PL + oB);
    acc = __builtin_amdgcn_mfma_f32_32x32x16_bf16(ah, bh, acc, 0, 0, 0);
    acc = __builtin_amdgcn_mfma_f32_32x32x16_bf16(ah, bl, acc, 0, 0, 0);
    acc = __builtin_amdgcn_mfma_f32_32x32x16_bf16(al, bh, acc, 0, 0, 0);
  }
}

// write regs [r0,r1) of a C-layout tile into a split slot.
// C/D layout (32x32): col = lane&31, row = (reg&3) + 8*(reg>>2) + 4*(lane>>5)
__device__ __forceinline__ void write_tile_split(char* slot, int R, int C, int lane,
                                                 const f32x16& vals, int r0, int r1) {
  const int col = C + (lane & 31);
  const int cchunk = col >> 3;
  const int cbyte = (col & 7) * 2;
  const int rbase = R + 4 * (lane >> 5);
#pragma unroll
  for (int r = 0; r < 16; ++r) {
    if (r < r0 || r >= r1) continue;
    int m = rbase + (r & 3) + 8 * (r >> 2);
    int off = m * 128 + ((cchunk ^ (m & 7)) << 4) + cbyte;
    float v = vals[r];
    unsigned int u = __float_as_uint(v);
    *(unsigned short*)(slot + off) = (unsigned short)(u >> 16);
    float hf = __uint_as_float(u & 0xFFFF0000u);
    float lo = v - hf;
    *(unsigned short*)(slot + PL + off) = (unsigned short)(__float_as_uint(lo) >> 16);
  }
}

__device__ __forceinline__ void store_identity16(char* slot, int m, int kc0) {
  float zi[16];
  int c0 = kc0 * 8;
#pragma unroll
  for (int i = 0; i < 16; ++i) zi[i] = (m == c0 + i) ? 1.f : 0.f;
  split_store8(slot, swadr(m, kc0), zi);
  split_store8(slot, swadr(m, kc0 + 1), zi + 8);
}

__global__ void __launch_bounds__(256)
spd_pool_kernel(const float* __restrict__ X, float* __restrict__ out) {
  __shared__ __align__(16) char lds[49152];
  char* Yp = lds;           // slot Y: hi plane + lo plane
  char* Zp = lds + 16384;   // slot Z
  char* Tp = lds + 32768;   // slot T (later E, later P)

  const int tid = threadIdx.x;
  const int lane = tid & 63;
  const int wv = tid >> 6;             // 4 waves
  const int R = (wv >> 1) * 32;        // tile row base
  const int Cc = (wv & 1) * 32;        // tile col base
  const int half = lane >> 5;
  const int ln31 = lane & 31;
  const int mA = R + ln31;             // A-frag row for this lane
  const int mB = Cc + ln31;            // B-frag row (symmetric operand)

  // elementwise mapping: each thread owns row em, 16 cols starting ec0
  const int em = tid >> 2;
  const int ekc = (tid & 3) * 2;       // first 16B chunk
  const int ec0 = ekc * 8;

  // ---------------- stage: Y = X/c1 (split), Z = I ----------------
  {
    const float* Xg = X + (size_t)blockIdx.x * 4096 + em * 64 + ec0;
    const float4* xp = (const float4*)Xg;
    float4 a = xp[0], b = xp[1], c = xp[2], d = xp[3];
    const float ic1 = 1.0f / 2.2f;
    float v[16] = {a.x * ic1, a.y * ic1, a.z * ic1, a.w * ic1,
                   b.x * ic1, b.y * ic1, b.z * ic1, b.w * ic1,
                   c.x * ic1, c.y * ic1, c.z * ic1, c.w * ic1,
                   d.x * ic1, d.y * ic1, d.z * ic1, d.w * ic1};
    split_store8(Yp, swadr(em, ekc), v);
    split_store8(Yp, swadr(em, ekc + 1), v + 8);
    store_identity16(Zp, em, ekc);
  }
  __syncthreads();

  // ---------------- Newton-Schulz levels ----------------
#pragma unroll 1
  for (int lvl = 0; lvl < 2; ++lvl) {
    const int iters = (lvl == 0) ? 9 : 5;
#pragma unroll 1
    for (int it = 0; it < iters; ++it) {
      // T = 1.5 I - 0.5 * Z*Y
      f32x16 acc = zero16();
      mac_tile<4>(acc, Zp, Yp, mA, mB, half);
      f32x16 tv;
#pragma unroll
      for (int r = 0; r < 16; ++r) {
        int m = R + (r & 3) + 8 * (r >> 2) + 4 * half;
        tv[r] = ((m == Cc + ln31) ? 1.5f : 0.f) - 0.5f * acc[r];
      }
      write_tile_split(Tp, R, Cc, lane, tv, 0, 16);
      __syncthreads();
      // Y' = Y*T ; Z' = T*Z (fused: all reads, barrier, then writes)
      f32x16 ay = zero16(), az = zero16();
      mac_tile<4>(ay, Yp, Tp, mA, mB, half);
      mac_tile<4>(az, Tp, Zp, mA, mB, half);
      __syncthreads();
      write_tile_split(Yp, R, Cc, lane, ay, 0, 16);
      write_tile_split(Zp, R, Cc, lane, az, 0, 16);
      __syncthreads();
    }
    if (lvl == 0) {
      // Y <- Y * sqrt(c1)/c2 ; Z <- I   (enter level 2)
      const float s12 = 0.92702481f;  // sqrt(2.2)/1.6
      float v[16];
      load_compose8(Yp, swadr(em, ekc), v);
      load_compose8(Yp, swadr(em, ekc + 1), v + 8);
#pragma unroll
      for (int i = 0; i < 16; ++i) v[i] *= s12;
      split_store8(Yp, swadr(em, ekc), v);
      split_store8(Yp, swadr(em, ekc + 1), v + 8);
      store_identity16(Zp, em, ekc);
      __syncthreads();
    }
  }

  // ---------------- E = sqrt(c2)*Y - I -> T ; q0 -> Z ----------------
  {
    const float s2 = 1.26491106f;  // sqrt(1.6)
    float v[16], e[16], q0[16];
    load_compose8(Yp, swadr(em, ekc), v);
    load_compose8(Yp, swadr(em, ekc + 1), v + 8);
#pragma unroll
    for (int i = 0; i < 16; ++i) {
      float dg = (em == ec0 + i) ? 1.f : 0.f;
      e[i] = s2 * v[i] - dg;
      q0[i] = (-1.f / 16.f) * e[i] + (1.f / 15.f) * dg;
    }
    split_store8(Tp, swadr(em, ekc), e);
    split_store8(Tp, swadr(em, ekc + 1), e + 8);
    split_store8(Zp, swadr(em, ekc), q0);
    split_store8(Zp, swadr(em, ekc + 1), q0 + 8);
  }
  __syncthreads();

  // ---------------- log Horner: q' = E*q + c_j I ----------------
  {
    char* q = Zp;
    char* qo = Yp;
#pragma unroll 1
    for (int j = 14; j >= 1; --j) {
      float coef = ((j & 1) ? 1.f : -1.f) / (float)j;
      f32x16 acc = zero16();
      mac_tile<4>(acc, Tp, q, mA, mB, half);
      f32x16 tv;
#pragma unroll
      for (int r = 0; r < 16; ++r) {
        int m = R + (r & 3) + 8 * (r >> 2) + 4 * half;
        tv[r] = acc[r] + ((m == Cc + ln31) ? coef : 0.f);
      }
      write_tile_split(qo, R, Cc, lane, tv, 0, 16);
      __syncthreads();
      char* t = q; q = qo; qo = t;
    }
    // L = 4 * E * q -> qo (== Yp after 14 swaps)
    f32x16 acc = zero16();
    mac_tile<4>(acc, Tp, q, mA, mB, half);
    f32x16 tv;
#pragma unroll
    for (int r = 0; r < 16; ++r) tv[r] = 4.f * acc[r];
    write_tile_split(qo, R, Cc, lane, tv, 0, 16);
    __syncthreads();
  }
  // L now in Yp

  // ---------------- pool 2x2 -> P (rows 0..31 of Tp), q2 init -> Zp ----------------
  {
    const float d12 = 1.f / 479001600.f;  // 1/12!
    const float d11 = 1.f / 39916800.f;   // 1/11!
    int i = tid >> 3, ct = tid & 7, j4 = ct * 4;
    float r0[8], r1[8];
    load_compose8(Yp, swadr(2 * i, ct), r0);
    load_compose8(Yp, swadr(2 * i + 1, ct), r1);
    float p[4], q2v[4];
#pragma unroll
    for (int qq = 0; qq < 4; ++qq) {
      p[qq] = 0.25f * (r0[2 * qq] + r0[2 * qq + 1] + r1[2 * qq] + r1[2 * qq + 1]);
      float dg = (i == j4 + qq) ? 1.f : 0.f;
      q2v[qq] = d12 * p[qq] + d11 * dg;
    }
    int boff = swadr(i, ct >> 1) + (j4 & 7) * 2;
    split_store4(Tp, boff, p);
    split_store4(Zp, boff, q2v);
  }
  __syncthreads();

  // ---------------- exp Horner on 32x32 (all waves redundant compute) ----------------
  {
    const float dfac[11] = {1.f,          1.f,           0.5f,
                            1.f / 6.f,    1.f / 24.f,    1.f / 120.f,
                            1.f / 720.f,  1.f / 5040.f,  1.f / 40320.f,
                            1.f / 362880.f, 1.f / 3628800.f};
    char* src = Zp;
    char* dst = Yp;
#pragma unroll 1
    for (int j = 10; j >= 1; --j) {
      f32x16 acc = zero16();
      mac_tile<2>(acc, Tp, src, ln31, ln31, half);
      f32x16 tv;
#pragma unroll
      for (int r = 0; r < 16; ++r) {
        int rl = (r & 3) + 8 * (r >> 2) + 4 * half;
        tv[r] = acc[r] + ((rl == ln31) ? dfac[j] : 0.f);
      }
      write_tile_split(dst, 0, 0, lane, tv, 4 * wv, 4 * wv + 4);
      __syncthreads();
      char* t = src; src = dst; dst = t;
    }
    // final term (j=0): result = P*q + I, straight to global (fp32)
    f32x16 acc = zero16();
    mac_tile<2>(acc, Tp, src, ln31, ln31, half);
    float* og = out + (size_t)blockIdx.x * 1024;
#pragma unroll
    for (int r = 0; r < 16; ++r) {
      if (r < 4 * wv || r >= 4 * wv + 4) continue;
      int rl = (r & 3) + 8 * (r >> 2) + 4 * half;
      og[rl * 32 + ln31] = acc[r] + ((rl == ln31) ? 1.f : 0.f);
    }
  }
}

extern "C" void kernel_launch(void* const* d_in, const int* in_sizes, int n_in,
                              void* d_out, int out_size, void* d_ws, size_t ws_size,
                              hipStream_t stream) {
  const float* X = (const float*)d_in[0];
  float* out = (float*)d_out;
  const int batch = in_sizes[0] / 4096;  // 8192
  spd_pool_kernel<<<batch, 256, 0, stream>>>(X, out);
}

// Round 3
// 918.981 us; speedup vs baseline: 3.3064x; 1.1465x over previous
//
#include <hip/hip_runtime.h>

typedef __attribute__((ext_vector_type(8))) short short8;
typedef __attribute__((ext_vector_type(4))) short short4v;
typedef __attribute__((ext_vector_type(16))) float f32x16;

#define PL 8256    // lo-plane offset: 8192 + 64B pad (shifts lo banks by 16)
#define SLOT 16448 // hi plane (8192) + pad(64) + lo plane (8192)

__device__ __forceinline__ int swadr(int m, int kc) {
  return m * 128 + ((kc ^ (m & 7)) << 4);
}

__device__ __forceinline__ f32x16 zero16() {
  f32x16 z;
#pragma unroll
  for (int i = 0; i < 16; ++i) z[i] = 0.f;
  return z;
}

__device__ __forceinline__ void split_store8(char* slot, int byteoff, const float* v) {
  short8 h, l;
#pragma unroll
  for (int i = 0; i < 8; ++i) {
    unsigned int u = __float_as_uint(v[i]);
    h[i] = (short)(u >> 16);
    float hf = __uint_as_float(u & 0xFFFF0000u);
    float lo = v[i] - hf;
    l[i] = (short)(__float_as_uint(lo) >> 16);
  }
  *(short8*)(slot + byteoff) = h;
  *(short8*)(slot + PL + byteoff) = l;
}

__device__ __forceinline__ void split_store4(char* slot, int byteoff, const float* v) {
  short4v h, l;
#pragma unroll
  for (int i = 0; i < 4; ++i) {
    unsigned int u = __float_as_uint(v[i]);
    h[i] = (short)(u >> 16);
    float hf = __uint_as_float(u & 0xFFFF0000u);
    float lo = v[i] - hf;
    l[i] = (short)(__float_as_uint(lo) >> 16);
  }
  *(short4v*)(slot + byteoff) = h;
  *(short4v*)(slot + PL + byteoff) = l;
}

__device__ __forceinline__ void load_compose8(const char* slot, int byteoff, float* v) {
  short8 h = *(const short8*)(slot + byteoff);
  short8 l = *(const short8*)(slot + PL + byteoff);
#pragma unroll
  for (int i = 0; i < 8; ++i) {
    unsigned int uh = ((unsigned int)(unsigned short)h[i]) << 16;
    unsigned int ul = ((unsigned int)(unsigned short)l[i]) << 16;
    v[i] = __uint_as_float(uh) + __uint_as_float(ul);
  }
}

// acc += A*B (B symmetric, read row-wise). 3-term split: AhBh + AhBl + AlBh.
template <int NK>
__device__ __forceinline__ void mac_tile(f32x16& acc, const char* A, const char* B,
                                         int mA, int mB, int half) {
  const int baseA = mA * 128, maskA = mA & 7;
  const int baseB = mB * 128, maskB = mB & 7;
#pragma unroll
  for (int s = 0; s < NK; ++s) {
    const int kc = 2 * s + half;
    const int oA = baseA + ((kc ^ maskA) << 4);
    const int oB = baseB + ((kc ^ maskB) << 4);
    short8 ah = *(const short8*)(A + oA);
    short8 al = *(const short8*)(A + PL + oA);
    short8 bh = *(const short8*)(B + oB);
    short8 bl = *(const short8*)(B + PL + oB);
    acc = __builtin_amdgcn_mfma_f32_32x32x16_bf16(ah, bh, acc, 0, 0, 0);
    acc = __builtin_amdgcn_mfma_f32_32x32x16_bf16(ah, bl, acc, 0, 0, 0);
    acc = __builtin_amdgcn_mfma_f32_32x32x16_bf16(al, bh, acc, 0, 0, 0);
  }
}

// Packed C-tile write: DPP lane-pair exchange; even lanes write packed hi
// words, odd lanes packed lo words (lo plane bank-shifted by +16).
__device__ __forceinline__ void write_tile_packed(char* slot, int R, int C, int lane,
                                                  const f32x16& vals, int r0, int r1) {
  const int ln31 = lane & 31;
  const bool ev = (ln31 & 1) == 0;
  const int col0 = C + (ln31 & ~1);
  const int cchunk = col0 >> 3;
  const int cbyte = (col0 & 7) * 2;
  const int rbase = R + 4 * (lane >> 5);
  const int pl = ev ? 0 : PL;
#pragma unroll
  for (int r = 0; r < 16; ++r) {
    if (r < r0 || r >= r1) continue;
    float v = vals[r];
    unsigned int u = __float_as_uint(v);
    unsigned int hu = u & 0xFFFF0000u;
    float lof = v - __uint_as_float(hu);
    unsigned int hs = hu >> 16;
    unsigned int ls = __float_as_uint(lof) >> 16;
    unsigned int hp = (unsigned int)__builtin_amdgcn_mov_dpp((int)hs, 0xB1, 0xF, 0xF, true);
    unsigned int lp = (unsigned int)__builtin_amdgcn_mov_dpp((int)ls, 0xB1, 0xF, 0xF, true);
    unsigned int word = ev ? (hs | (hp << 16)) : (lp | (ls << 16));
    int m = rbase + (r & 3) + 8 * (r >> 2);
    int off = m * 128 + ((cchunk ^ (m & 7)) << 4) + cbyte;
    *(unsigned int*)(slot + pl + off) = word;
  }
}

__global__ void __launch_bounds__(256)
spd_pool_kernel(const float* __restrict__ X, float* __restrict__ out) {
  __shared__ __align__(16) char lds[3 * SLOT];
  char* Yp = lds;
  char* Zp = lds + SLOT;
  char* Tp = lds + 2 * SLOT;

  const int tid = threadIdx.x;
  const int lane = tid & 63;
  const int wv = tid >> 6;
  const int R = (wv >> 1) * 32;
  const int Cc = (wv & 1) * 32;
  const int half = lane >> 5;
  const int ln31 = lane & 31;
  const int mA = R + ln31;
  const int mB = Cc + ln31;

  const int em = tid >> 2;
  const int ekc = (tid & 3) * 2;
  const int ec0 = ekc * 8;

  // ---- stage 0: Y = X/c1, Z = T0 = 1.5I - 0.5Y (Z0=I shortcut) ----
  {
    const float ic1 = 1.0f / 6.6f;
    const float* Xg = X + (size_t)blockIdx.x * 4096 + em * 64 + ec0;
    const float4* xp = (const float4*)Xg;
    float4 a = xp[0], b = xp[1], c = xp[2], d = xp[3];
    float v[16] = {a.x * ic1, a.y * ic1, a.z * ic1, a.w * ic1,
                   b.x * ic1, b.y * ic1, b.z * ic1, b.w * ic1,
                   c.x * ic1, c.y * ic1, c.z * ic1, c.w * ic1,
                   d.x * ic1, d.y * ic1, d.z * ic1, d.w * ic1};
    float t[16];
#pragma unroll
    for (int i = 0; i < 16; ++i)
      t[i] = ((em == ec0 + i) ? 1.5f : 0.f) - 0.5f * v[i];
    split_store8(Yp, swadr(em, ekc), v);
    split_store8(Yp, swadr(em, ekc + 1), v + 8);
    split_store8(Zp, swadr(em, ekc), t);
    split_store8(Zp, swadr(em, ekc + 1), t + 8);
  }
  __syncthreads();
  // iter1: Y <- Y*T0 (in place); Z already holds Z1=T0
  {
    f32x16 acc = zero16();
    mac_tile<4>(acc, Yp, Zp, mA, mB, half);
    __syncthreads();
    write_tile_packed(Yp, R, Cc, lane, acc, 0, 16);
    __syncthreads();
  }
  // ---- level 1: 6 more iterations; last skips dead Z-update ----
#pragma unroll 1
  for (int it = 0; it < 6; ++it) {
    f32x16 acc = zero16();
    mac_tile<4>(acc, Zp, Yp, mA, mB, half);
    f32x16 tv;
#pragma unroll
    for (int r = 0; r < 16; ++r) {
      int m = R + (r & 3) + 8 * (r >> 2) + 4 * half;
      tv[r] = ((m == Cc + ln31) ? 1.5f : 0.f) - 0.5f * acc[r];
    }
    write_tile_packed(Tp, R, Cc, lane, tv, 0, 16);
    __syncthreads();
    if (it < 5) {
      f32x16 ay = zero16(), az = zero16();
      mac_tile<4>(ay, Yp, Tp, mA, mB, half);
      mac_tile<4>(az, Tp, Zp, mA, mB, half);
      __syncthreads();
      write_tile_packed(Yp, R, Cc, lane, ay, 0, 16);
      write_tile_packed(Zp, R, Cc, lane, az, 0, 16);
      __syncthreads();
    } else {
      f32x16 ay = zero16();
      mac_tile<4>(ay, Yp, Tp, mA, mB, half);
      __syncthreads();
      write_tile_packed(Yp, R, Cc, lane, ay, 0, 16);
      __syncthreads();
    }
  }
  // ---- level transition: Y *= sqrt(c1)/c2 ; Z = 1.5I - 0.5Y ----
  {
    const float s12 = 1.0317054f;  // sqrt(6.6)/2.49
    float v[16], t[16];
    load_compose8(Yp, swadr(em, ekc), v);
    load_compose8(Yp, swadr(em, ekc + 1), v + 8);
#pragma unroll
    for (int i = 0; i < 16; ++i) {
      v[i] *= s12;
      t[i] = ((em == ec0 + i) ? 1.5f : 0.f) - 0.5f * v[i];
    }
    split_store8(Yp, swadr(em, ekc), v);
    split_store8(Yp, swadr(em, ekc + 1), v + 8);
    split_store8(Zp, swadr(em, ekc), t);
    split_store8(Zp, swadr(em, ekc + 1), t + 8);
  }
  __syncthreads();
  // level-2 iter1: Y <- Y*T0 (in place)
  {
    f32x16 acc = zero16();
    mac_tile<4>(acc, Yp, Zp, mA, mB, half);
    __syncthreads();
    write_tile_packed(Yp, R, Cc, lane, acc, 0, 16);
    __syncthreads();
  }
  // ---- level 2: 4 full iterations (need both Y and Z at end) ----
#pragma unroll 1
  for (int it = 0; it < 4; ++it) {
    f32x16 acc = zero16();
    mac_tile<4>(acc, Zp, Yp, mA, mB, half);
    f32x16 tv;
#pragma unroll
    for (int r = 0; r < 16; ++r) {
      int m = R + (r & 3) + 8 * (r >> 2) + 4 * half;
      tv[r] = ((m == Cc + ln31) ? 1.5f : 0.f) - 0.5f * acc[r];
    }
    write_tile_packed(Tp, R, Cc, lane, tv, 0, 16);
    __syncthreads();
    f32x16 ay = zero16(), az = zero16();
    mac_tile<4>(ay, Yp, Tp, mA, mB, half);
    mac_tile<4>(az, Tp, Zp, mA, mB, half);
    __syncthreads();
    write_tile_packed(Yp, R, Cc, lane, ay, 0, 16);
    write_tile_packed(Zp, R, Cc, lane, az, 0, 16);
    __syncthreads();
  }
  // ---- S = 0.5*(sqrt(c2)*Y - Z/sqrt(c2)) -> Tp ----
  {
    const float ca = 0.7889867f;  // 0.5*sqrt(2.49)
    const float cb = 0.3168620f;  // 0.5/sqrt(2.49)
    float y[16], z[16], s[16];
    load_compose8(Yp, swadr(em, ekc), y);
    load_compose8(Yp, swadr(em, ekc + 1), y + 8);
    load_compose8(Zp, swadr(em, ekc), z);
    load_compose8(Zp, swadr(em, ekc + 1), z + 8);
#pragma unroll
    for (int i = 0; i < 16; ++i) s[i] = ca * y[i] - cb * z[i];
    split_store8(Tp, swadr(em, ekc), s);
    split_store8(Tp, swadr(em, ekc + 1), s + 8);
  }
  __syncthreads();
  // ---- S2 = S*S -> Yp ----
  {
    f32x16 acc = zero16();
    mac_tile<4>(acc, Tp, Tp, mA, mB, half);
    write_tile_packed(Yp, R, Cc, lane, acc, 0, 16);
    __syncthreads();
  }
  // ---- q = a11*S2 + a9*I -> Zp ----
  {
    const float a11 = -0.08948864f, a9 = 0.12152778f;
    float v[16], q[16];
    load_compose8(Yp, swadr(em, ekc), v);
    load_compose8(Yp, swadr(em, ekc + 1), v + 8);
#pragma unroll
    for (int i = 0; i < 16; ++i)
      q[i] = a11 * v[i] + ((em == ec0 + i) ? a9 : 0.f);
    split_store8(Zp, swadr(em, ekc), q);
    split_store8(Zp, swadr(em, ekc + 1), q + 8);
  }
  __syncthreads();
  // ---- asinh Horner: 4x in-place q = q*S2 + c*I  (L/S scale 4 folded in) ----
  {
    const float acoef[4] = {-0.17857143f, 0.3f, -0.66666667f, 4.f};
#pragma unroll 1
    for (int j = 0; j < 4; ++j) {
      f32x16 acc = zero16();
      mac_tile<4>(acc, Zp, Yp, mA, mB, half);
      f32x16 tv;
#pragma unroll
      for (int r = 0; r < 16; ++r) {
        int m = R + (r & 3) + 8 * (r >> 2) + 4 * half;
        tv[r] = acc[r] + ((m == Cc + ln31) ? acoef[j] : 0.f);
      }
      __syncthreads();
      write_tile_packed(Zp, R, Cc, lane, tv, 0, 16);
      __syncthreads();
    }
  }
  // ---- L = S*q -> Yp  (L = 4*asinh(S) via scaled coeffs) ----
  {
    f32x16 acc = zero16();
    mac_tile<4>(acc, Tp, Zp, mA, mB, half);
    write_tile_packed(Yp, R, Cc, lane, acc, 0, 16);
    __syncthreads();
  }
  // ---- pool -> P2 = P/2 (Tp rows 0..31); q2 = d8*P2 + d7*I -> Zp ----
  {
    const float d8 = 2.4801587e-5f, d7 = 1.9841270e-4f;
    int i = tid >> 3, ct = tid & 7, j4 = ct * 4;
    float r0[8], r1[8];
    load_compose8(Yp, swadr(2 * i, ct), r0);
    load_compose8(Yp, swadr(2 * i + 1, ct), r1);
    float p[4], q2v[4];
#pragma unroll
    for (int qq = 0; qq < 4; ++qq) {
      p[qq] = 0.125f * (r0[2 * qq] + r0[2 * qq + 1] + r1[2 * qq] + r1[2 * qq + 1]);
      q2v[qq] = d8 * p[qq] + ((i == j4 + qq) ? d7 : 0.f);
    }
    int boff = swadr(i, ct >> 1) + (j4 & 7) * 2;
    split_store4(Tp, boff, p);
    split_store4(Zp, boff, q2v);
  }
  __syncthreads();
  // ---- exp(P/2) Horner: 7x in-place q2 = q2*P2 + d*I ----
  {
    const float dcoef[7] = {1.f / 720.f, 1.f / 120.f, 1.f / 24.f,
                            1.f / 6.f,   0.5f,        1.f,       1.f};
#pragma unroll 1
    for (int j = 0; j < 7; ++j) {
      f32x16 acc = zero16();
      mac_tile<2>(acc, Zp, Tp, ln31, ln31, half);
      f32x16 tv;
#pragma unroll
      for (int r = 0; r < 16; ++r) {
        int rl = (r & 3) + 8 * (r >> 2) + 4 * half;
        tv[r] = acc[r] + ((rl == ln31) ? dcoef[j] : 0.f);
      }
      __syncthreads();
      write_tile_packed(Zp, 0, 0, lane, tv, 4 * wv, 4 * wv + 4);
      __syncthreads();
    }
  }
  // ---- OUT = H*H (squaring undoes the halving), direct to global ----
  {
    f32x16 acc = zero16();
    mac_tile<2>(acc, Zp, Zp, ln31, ln31, half);
    float* og = out + (size_t)blockIdx.x * 1024;
#pragma unroll
    for (int r = 0; r < 16; ++r) {
      if (r < 4 * wv || r >= 4 * wv + 4) continue;
      int rl = (r & 3) + 8 * (r >> 2) + 4 * half;
      og[rl * 32 + ln31] = acc[r];
    }
  }
}

extern "C" void kernel_launch(void* const* d_in, const int* in_sizes, int n_in,
                              void* d_out, int out_size, void* d_ws, size_t ws_size,
                              hipStream_t stream) {
  const float* X = (const float*)d_in[0];
  float* out = (float*)d_out;
  const int batch = in_sizes[0] / 4096;  // 8192
  spd_pool_kernel<<<batch, 256, 0, stream>>>(X, out);
}

// Round 4
// 671.765 us; speedup vs baseline: 4.5232x; 1.3680x over previous
//
#include <hip/hip_runtime.h>

typedef __attribute__((ext_vector_type(8))) short short8;
typedef __attribute__((ext_vector_type(4))) short short4v;
typedef __attribute__((ext_vector_type(16))) float f32x16;

#define PL 8256    // lo-plane offset: 8192 + 64B pad (bank shift by 16)
#define SLOT 16448 // hi(8192) + pad(64) + lo(8192)

__device__ __forceinline__ int swadr(int m, int kc) {
  return m * 128 + ((kc ^ (m & 7)) << 4);
}

__device__ __forceinline__ f32x16 zero16() {
  f32x16 z;
#pragma unroll
  for (int i = 0; i < 16; ++i) z[i] = 0.f;
  return z;
}

__device__ __forceinline__ unsigned short rne16(float v) {
  unsigned int u = __float_as_uint(v);
  return (unsigned short)((u + 0x7FFFu + ((u >> 16) & 1)) >> 16);
}

// ---- split (truncation) store/compose on a SLOT (hi + lo planes) ----
__device__ __forceinline__ void split_store8(char* slot, int byteoff, const float* v) {
  short8 h, l;
#pragma unroll
  for (int i = 0; i < 8; ++i) {
    unsigned int u = __float_as_uint(v[i]);
    h[i] = (short)(u >> 16);
    float hf = __uint_as_float(u & 0xFFFF0000u);
    float lo = v[i] - hf;
    l[i] = (short)(__float_as_uint(lo) >> 16);
  }
  *(short8*)(slot + byteoff) = h;
  *(short8*)(slot + PL + byteoff) = l;
}

__device__ __forceinline__ void split_store4(char* slot, int byteoff, const float* v) {
  short4v h, l;
#pragma unroll
  for (int i = 0; i < 4; ++i) {
    unsigned int u = __float_as_uint(v[i]);
    h[i] = (short)(u >> 16);
    float hf = __uint_as_float(u & 0xFFFF0000u);
    float lo = v[i] - hf;
    l[i] = (short)(__float_as_uint(lo) >> 16);
  }
  *(short4v*)(slot + byteoff) = h;
  *(short4v*)(slot + PL + byteoff) = l;
}

__device__ __forceinline__ void load_compose8(const char* slot, int byteoff, float* v) {
  short8 h = *(const short8*)(slot + byteoff);
  short8 l = *(const short8*)(slot + PL + byteoff);
#pragma unroll
  for (int i = 0; i < 8; ++i) {
    unsigned int uh = ((unsigned int)(unsigned short)h[i]) << 16;
    unsigned int ul = ((unsigned int)(unsigned short)l[i]) << 16;
    v[i] = __uint_as_float(uh) + __uint_as_float(ul);
  }
}

// bf16 (RNE) store of 8 floats into a single PLANE
__device__ __forceinline__ void store_hi8(char* plane, int byteoff, const float* v) {
  short8 h;
#pragma unroll
  for (int i = 0; i < 8; ++i) h[i] = (short)rne16(v[i]);
  *(short8*)(plane + byteoff) = h;
}

// ---- MFMA macs on PLANE pointers (B symmetric -> row-read) ----
template <int NK>
__device__ __forceinline__ void mac1(f32x16& acc, const char* Ah, const char* Bh,
                                     int mA, int mB, int half) {
  const int baseA = mA * 128, maskA = mA & 7;
  const int baseB = mB * 128, maskB = mB & 7;
#pragma unroll
  for (int s = 0; s < NK; ++s) {
    int kc = 2 * s + half;
    short8 a = *(const short8*)(Ah + baseA + ((kc ^ maskA) << 4));
    short8 b = *(const short8*)(Bh + baseB + ((kc ^ maskB) << 4));
    acc = __builtin_amdgcn_mfma_f32_32x32x16_bf16(a, b, acc, 0, 0, 0);
  }
}

template <int NK>  // A split, B bf16
__device__ __forceinline__ void mac2A(f32x16& acc, const char* Ah, const char* Al,
                                      const char* Bh, int mA, int mB, int half) {
  const int baseA = mA * 128, maskA = mA & 7;
  const int baseB = mB * 128, maskB = mB & 7;
#pragma unroll
  for (int s = 0; s < NK; ++s) {
    int kc = 2 * s + half;
    int oA = baseA + ((kc ^ maskA) << 4);
    short8 ah = *(const short8*)(Ah + oA);
    short8 al = *(const short8*)(Al + oA);
    short8 b = *(const short8*)(Bh + baseB + ((kc ^ maskB) << 4));
    acc = __builtin_amdgcn_mfma_f32_32x32x16_bf16(ah, b, acc, 0, 0, 0);
    acc = __builtin_amdgcn_mfma_f32_32x32x16_bf16(al, b, acc, 0, 0, 0);
  }
}

template <int NK>  // A bf16, B split
__device__ __forceinline__ void mac2B(f32x16& acc, const char* Ah, const char* Bh,
                                      const char* Bl, int mA, int mB, int half) {
  const int baseA = mA * 128, maskA = mA & 7;
  const int baseB = mB * 128, maskB = mB & 7;
#pragma unroll
  for (int s = 0; s < NK; ++s) {
    int kc = 2 * s + half;
    int oB = baseB + ((kc ^ maskB) << 4);
    short8 a = *(const short8*)(Ah + baseA + ((kc ^ maskA) << 4));
    short8 bh = *(const short8*)(Bh + oB);
    short8 bl = *(const short8*)(Bl + oB);
    acc = __builtin_amdgcn_mfma_f32_32x32x16_bf16(a, bh, acc, 0, 0, 0);
    acc = __builtin_amdgcn_mfma_f32_32x32x16_bf16(a, bl, acc, 0, 0, 0);
  }
}

template <int NK>  // both split
__device__ __forceinline__ void mac3(f32x16& acc, const char* Ah, const char* Al,
                                     const char* Bh, const char* Bl,
                                     int mA, int mB, int half) {
  const int baseA = mA * 128, maskA = mA & 7;
  const int baseB = mB * 128, maskB = mB & 7;
#pragma unroll
  for (int s = 0; s < NK; ++s) {
    int kc = 2 * s + half;
    int oA = baseA + ((kc ^ maskA) << 4);
    int oB = baseB + ((kc ^ maskB) << 4);
    short8 ah = *(const short8*)(Ah + oA);
    short8 al = *(const short8*)(Al + oA);
    short8 bh = *(const short8*)(Bh + oB);
    short8 bl = *(const short8*)(Bl + oB);
    acc = __builtin_amdgcn_mfma_f32_32x32x16_bf16(ah, bh, acc, 0, 0, 0);
    acc = __builtin_amdgcn_mfma_f32_32x32x16_bf16(ah, bl, acc, 0, 0, 0);
    acc = __builtin_amdgcn_mfma_f32_32x32x16_bf16(al, bh, acc, 0, 0, 0);
  }
}

// split write of C-tile (both planes), DPP lane-pair packed b32
__device__ __forceinline__ void write_split(char* slot, int R, int C, int lane,
                                            const f32x16& vals, int r0, int r1) {
  const int ln31 = lane & 31;
  const bool ev = (ln31 & 1) == 0;
  const int col0 = C + (ln31 & ~1);
  const int cchunk = col0 >> 3;
  const int cbyte = (col0 & 7) * 2;
  const int rbase = R + 4 * (lane >> 5);
  const int pl = ev ? 0 : PL;
#pragma unroll
  for (int r = 0; r < 16; ++r) {
    if (r < r0 || r >= r1) continue;
    float v = vals[r];
    unsigned int u = __float_as_uint(v);
    unsigned int hu = u & 0xFFFF0000u;
    float lof = v - __uint_as_float(hu);
    unsigned int hs = hu >> 16;
    unsigned int ls = __float_as_uint(lof) >> 16;
    unsigned int hp = (unsigned int)__builtin_amdgcn_mov_dpp((int)hs, 0xB1, 0xF, 0xF, true);
    unsigned int lp = (unsigned int)__builtin_amdgcn_mov_dpp((int)ls, 0xB1, 0xF, 0xF, true);
    unsigned int word = ev ? (hs | (hp << 16)) : (lp | (ls << 16));
    int m = rbase + (r & 3) + 8 * (r >> 2);
    int off = m * 128 + ((cchunk ^ (m & 7)) << 4) + cbyte;
    *(unsigned int*)(slot + pl + off) = word;
  }
}

// bf16-only C-tile write into one PLANE: even lanes store packed pairs (RNE)
__device__ __forceinline__ void write_hi(char* plane, int R, int C, int lane,
                                         const f32x16& vals) {
  const int ln31 = lane & 31;
  const bool ev = (ln31 & 1) == 0;
  const int col0 = C + (ln31 & ~1);
  const int cchunk = col0 >> 3;
  const int cbyte = (col0 & 7) * 2;
  const int rbase = R + 4 * (lane >> 5);
#pragma unroll
  for (int r = 0; r < 16; ++r) {
    unsigned int hs = rne16(vals[r]);
    unsigned int hp = (unsigned int)__builtin_amdgcn_mov_dpp((int)hs, 0xB1, 0xF, 0xF, true);
    if (ev) {
      int m = rbase + (r & 3) + 8 * (r >> 2);
      *(unsigned int*)(plane + m * 128 + ((cchunk ^ (m & 7)) << 4) + cbyte) =
          hs | (hp << 16);
    }
  }
}

__global__ void __launch_bounds__(256)
spd_pool_kernel(const float* __restrict__ X, float* __restrict__ out) {
  __shared__ __align__(16) char lds[3 * SLOT];
  char* U0 = lds;
  char* U1 = lds + SLOT;
  char* U2 = lds + 2 * SLOT;

  const int tid = threadIdx.x;
  const int lane = tid & 63;
  const int wv = tid >> 6;
  const int R = (wv >> 1) * 32;
  const int Cc = (wv & 1) * 32;
  const int half = lane >> 5;
  const int ln31 = lane & 31;
  const int mA = R + ln31;
  const int mB = Cc + ln31;

  const int em = tid >> 2;
  const int ekc = (tid & 3) * 2;
  const int ec0 = ekc * 8;

  // ======= L1 init: U0 = X' = X/6.6 (split); U1h = Z1 = T0; U2lo = T0 =======
  {
    const float ic1 = 1.0f / 6.6f;
    const float* Xg = X + (size_t)blockIdx.x * 4096 + em * 64 + ec0;
    const float4* xp = (const float4*)Xg;
    float4 a = xp[0], b = xp[1], c = xp[2], d = xp[3];
    float v[16] = {a.x * ic1, a.y * ic1, a.z * ic1, a.w * ic1,
                   b.x * ic1, b.y * ic1, b.z * ic1, b.w * ic1,
                   c.x * ic1, c.y * ic1, c.z * ic1, c.w * ic1,
                   d.x * ic1, d.y * ic1, d.z * ic1, d.w * ic1};
    float t[16];
#pragma unroll
    for (int i = 0; i < 16; ++i)
      t[i] = ((em == ec0 + i) ? 1.5f : 0.f) - 0.5f * v[i];
    split_store8(U0, swadr(em, ekc), v);
    split_store8(U0, swadr(em, ekc + 1), v + 8);
    store_hi8(U1, swadr(em, ekc), t);
    store_hi8(U1, swadr(em, ekc + 1), t + 8);
    store_hi8(U2 + PL, swadr(em, ekc), t);
    store_hi8(U2 + PL, swadr(em, ekc + 1), t + 8);
  }
  __syncthreads();
  // iter1: Y = X'h * T0 -> U2h
  {
    f32x16 acc = zero16();
    mac1<4>(acc, U0, U2 + PL, mA, mB, half);
    write_hi(U2, R, Cc, lane, acc);
  }
  __syncthreads();
  // iters 2..5 bf16 coupled (Y=U2h, Z=U1h, T=U2lo)
#pragma unroll 1
  for (int it = 0; it < 4; ++it) {
    f32x16 a = zero16();
    mac1<4>(a, U1, U2, mA, mB, half);  // Z*Y
    f32x16 tv;
#pragma unroll
    for (int r = 0; r < 16; ++r) {
      int m = R + (r & 3) + 8 * (r >> 2) + 4 * half;
      tv[r] = ((m == Cc + ln31) ? 1.5f : 0.f) - 0.5f * a[r];
    }
    write_hi(U2 + PL, R, Cc, lane, tv);
    __syncthreads();
    f32x16 ay = zero16(), az = zero16();
    mac1<4>(ay, U2, U2 + PL, mA, mB, half);  // Y*T
    mac1<4>(az, U2 + PL, U1, mA, mB, half);  // T*Z
    __syncthreads();
    write_hi(U2, R, Cc, lane, ay);
    write_hi(U1, R, Cc, lane, az);
    __syncthreads();
  }
  // restore invariant: Y = X' * Z -> U2 (split)
  {
    f32x16 acc = zero16();
    mac2A<4>(acc, U0, U0 + PL, U1, mA, mB, half);
    write_split(U2, R, Cc, lane, acc, 0, 16);
  }
  __syncthreads();
  // iter6 (split; Z still bf16-only). T -> U0 (X' dead)
  {
    f32x16 a = zero16();
    mac2B<4>(a, U1, U2, U2 + PL, mA, mB, half);  // Zh*(Yh+Yl)
    f32x16 tv;
#pragma unroll
    for (int r = 0; r < 16; ++r) {
      int m = R + (r & 3) + 8 * (r >> 2) + 4 * half;
      tv[r] = ((m == Cc + ln31) ? 1.5f : 0.f) - 0.5f * a[r];
    }
    write_split(U0, R, Cc, lane, tv, 0, 16);
    __syncthreads();
    f32x16 ay = zero16(), az = zero16();
    mac3<4>(ay, U2, U2 + PL, U0, U0 + PL, mA, mB, half);  // Y*T
    mac2A<4>(az, U0, U0 + PL, U1, mA, mB, half);          // T*Zh
    __syncthreads();
    write_split(U2, R, Cc, lane, ay, 0, 16);
    write_split(U1, R, Cc, lane, az, 0, 16);
    __syncthreads();
  }
  // iter7 (split, no Z update; Y1 -> U2)
  {
    f32x16 a = zero16();
    mac3<4>(a, U1, U1 + PL, U2, U2 + PL, mA, mB, half);
    f32x16 tv;
#pragma unroll
    for (int r = 0; r < 16; ++r) {
      int m = R + (r & 3) + 8 * (r >> 2) + 4 * half;
      tv[r] = ((m == Cc + ln31) ? 1.5f : 0.f) - 0.5f * a[r];
    }
    write_split(U0, R, Cc, lane, tv, 0, 16);
    __syncthreads();
    f32x16 ay = zero16();
    mac3<4>(ay, U2, U2 + PL, U0, U0 + PL, mA, mB, half);
    __syncthreads();
    write_split(U2, R, Cc, lane, ay, 0, 16);
    __syncthreads();
  }

  // ======= L2 on X2' = Y1 (U2 split, spectrum [0.389,0.993], no rescale) ====
  // roles: Y=U0h, Z=U1h, T=U0lo
  {
    float y[16], t[16];
    load_compose8(U2, swadr(em, ekc), y);
    load_compose8(U2, swadr(em, ekc + 1), y + 8);
#pragma unroll
    for (int i = 0; i < 16; ++i)
      t[i] = ((em == ec0 + i) ? 1.5f : 0.f) - 0.5f * y[i];
    store_hi8(U1, swadr(em, ekc), t);
    store_hi8(U1, swadr(em, ekc + 1), t + 8);
    store_hi8(U0 + PL, swadr(em, ekc), t);
    store_hi8(U0 + PL, swadr(em, ekc + 1), t + 8);
  }
  __syncthreads();
  // iter1: Y = X2'h * T0 -> U0h
  {
    f32x16 acc = zero16();
    mac1<4>(acc, U2, U0 + PL, mA, mB, half);
    write_hi(U0, R, Cc, lane, acc);
  }
  __syncthreads();
  // iters 2..3 bf16
#pragma unroll 1
  for (int it = 0; it < 2; ++it) {
    f32x16 a = zero16();
    mac1<4>(a, U1, U0, mA, mB, half);
    f32x16 tv;
#pragma unroll
    for (int r = 0; r < 16; ++r) {
      int m = R + (r & 3) + 8 * (r >> 2) + 4 * half;
      tv[r] = ((m == Cc + ln31) ? 1.5f : 0.f) - 0.5f * a[r];
    }
    write_hi(U0 + PL, R, Cc, lane, tv);
    __syncthreads();
    f32x16 ay = zero16(), az = zero16();
    mac1<4>(ay, U0, U0 + PL, mA, mB, half);
    mac1<4>(az, U0 + PL, U1, mA, mB, half);
    __syncthreads();
    write_hi(U0, R, Cc, lane, ay);
    write_hi(U1, R, Cc, lane, az);
    __syncthreads();
  }
  // restore: Y2 = X2' * Z -> U0 (split)
  {
    f32x16 acc = zero16();
    mac2A<4>(acc, U2, U2 + PL, U1, mA, mB, half);
    write_split(U0, R, Cc, lane, acc, 0, 16);
  }
  __syncthreads();
  // iter4 (split; Z bf16). T -> U2 (X2' dead)
  {
    f32x16 a = zero16();
    mac2B<4>(a, U1, U0, U0 + PL, mA, mB, half);
    f32x16 tv;
#pragma unroll
    for (int r = 0; r < 16; ++r) {
      int m = R + (r & 3) + 8 * (r >> 2) + 4 * half;
      tv[r] = ((m == Cc + ln31) ? 1.5f : 0.f) - 0.5f * a[r];
    }
    write_split(U2, R, Cc, lane, tv, 0, 16);
    __syncthreads();
    f32x16 ay = zero16(), az = zero16();
    mac3<4>(ay, U0, U0 + PL, U2, U2 + PL, mA, mB, half);
    mac2A<4>(az, U2, U2 + PL, U1, mA, mB, half);
    __syncthreads();
    write_split(U0, R, Cc, lane, ay, 0, 16);
    write_split(U1, R, Cc, lane, az, 0, 16);
    __syncthreads();
  }
  // iter5 (full split; need Y2 AND Z2)
  {
    f32x16 a = zero16();
    mac3<4>(a, U1, U1 + PL, U0, U0 + PL, mA, mB, half);
    f32x16 tv;
#pragma unroll
    for (int r = 0; r < 16; ++r) {
      int m = R + (r & 3) + 8 * (r >> 2) + 4 * half;
      tv[r] = ((m == Cc + ln31) ? 1.5f : 0.f) - 0.5f * a[r];
    }
    write_split(U2, R, Cc, lane, tv, 0, 16);
    __syncthreads();
    f32x16 ay = zero16(), az = zero16();
    mac3<4>(ay, U0, U0 + PL, U2, U2 + PL, mA, mB, half);
    mac3<4>(az, U2, U2 + PL, U1, U1 + PL, mA, mB, half);
    __syncthreads();
    write_split(U0, R, Cc, lane, ay, 0, 16);
    write_split(U1, R, Cc, lane, az, 0, 16);
    __syncthreads();
  }

  // ======= S = ca*Y2 - cb*Z2 -> U2 (split) =======
  {
    const float ca = 0.80141224f;  // 6.6^{1/4}/2
    const float cb = 0.31194493f;  // 1/(2*6.6^{1/4})
    float y[16], z[16], s[16];
    load_compose8(U0, swadr(em, ekc), y);
    load_compose8(U0, swadr(em, ekc + 1), y + 8);
    load_compose8(U1, swadr(em, ekc), z);
    load_compose8(U1, swadr(em, ekc + 1), z + 8);
#pragma unroll
    for (int i = 0; i < 16; ++i) s[i] = ca * y[i] - cb * z[i];
    split_store8(U2, swadr(em, ekc), s);
    split_store8(U2, swadr(em, ekc + 1), s + 8);
  }
  __syncthreads();
  // S2 = S*S -> U0 (split)
  {
    f32x16 acc = zero16();
    mac3<4>(acc, U2, U2 + PL, U2, U2 + PL, mA, mB, half);
    write_split(U0, R, Cc, lane, acc, 0, 16);
  }
  __syncthreads();
  // q init = A11*S2 + A9*I -> U1h (bf16)
  {
    const float A11 = -0.08948864f, A9 = 0.12152778f;
    float v[16], q[16];
    load_compose8(U0, swadr(em, ekc), v);
    load_compose8(U0, swadr(em, ekc + 1), v + 8);
#pragma unroll
    for (int i = 0; i < 16; ++i)
      q[i] = A11 * v[i] + ((em == ec0 + i) ? A9 : 0.f);
    store_hi8(U1, swadr(em, ekc), q);
    store_hi8(U1, swadr(em, ekc + 1), q + 8);
  }
  __syncthreads();
  // asinh Horner steps A7,A5,A3 (bf16, contractive in S2)
  {
    const float acoef[3] = {-0.17857143f, 0.3f, -0.66666667f};
#pragma unroll 1
    for (int j = 0; j < 3; ++j) {
      f32x16 acc = zero16();
      mac1<4>(acc, U1, U0, mA, mB, half);
      f32x16 tv;
#pragma unroll
      for (int r = 0; r < 16; ++r) {
        int m = R + (r & 3) + 8 * (r >> 2) + 4 * half;
        tv[r] = acc[r] + ((m == Cc + ln31) ? acoef[j] : 0.f);
      }
      __syncthreads();
      write_hi(U1, R, Cc, lane, tv);
      __syncthreads();
    }
  }
  // last step: q = q*S2 + 4I -> U1 (split)
  {
    f32x16 acc = zero16();
    mac2B<4>(acc, U1, U0, U0 + PL, mA, mB, half);
    f32x16 tv;
#pragma unroll
    for (int r = 0; r < 16; ++r) {
      int m = R + (r & 3) + 8 * (r >> 2) + 4 * half;
      tv[r] = acc[r] + ((m == Cc + ln31) ? 4.f : 0.f);
    }
    __syncthreads();
    write_split(U1, R, Cc, lane, tv, 0, 16);
    __syncthreads();
  }
  // L = S*q -> U0 (split)
  {
    f32x16 acc = zero16();
    mac3<4>(acc, U2, U2 + PL, U1, U1 + PL, mA, mB, half);
    write_split(U0, R, Cc, lane, acc, 0, 16);
  }
  __syncthreads();
  // pool -> P2 = P/2 (U2 rows 0..31, split); q2 = d8*P2 + d7*I -> U1
  {
    const float d8 = 2.4801587e-5f, d7 = 1.9841270e-4f;
    int i = tid >> 3, ct = tid & 7, j4 = ct * 4;
    float r0[8], r1[8];
    load_compose8(U0, swadr(2 * i, ct), r0);
    load_compose8(U0, swadr(2 * i + 1, ct), r1);
    float p[4], q2v[4];
#pragma unroll
    for (int qq = 0; qq < 4; ++qq) {
      p[qq] = 0.125f * (r0[2 * qq] + r0[2 * qq + 1] + r1[2 * qq] + r1[2 * qq + 1]);
      q2v[qq] = d8 * p[qq] + ((i == j4 + qq) ? d7 : 0.f);
    }
    int boff = swadr(i, ct >> 1) + (j4 & 7) * 2;
    split_store4(U2, boff, p);
    split_store4(U1, boff, q2v);
  }
  __syncthreads();
  // exp(P/2) Horner, 7 in-place steps (split, 32x32)
  {
    const float dcoef[7] = {1.f / 720.f, 1.f / 120.f, 1.f / 24.f,
                            1.f / 6.f,   0.5f,        1.f,       1.f};
#pragma unroll 1
    for (int j = 0; j < 7; ++j) {
      f32x16 acc = zero16();
      mac3<2>(acc, U1, U1 + PL, U2, U2 + PL, ln31, ln31, half);
      f32x16 tv;
#pragma unroll
      for (int r = 0; r < 16; ++r) {
        int rl = (r & 3) + 8 * (r >> 2) + 4 * half;
        tv[r] = acc[r] + ((rl == ln31) ? dcoef[j] : 0.f);
      }
      __syncthreads();
      write_split(U1, 0, 0, lane, tv, 4 * wv, 4 * wv + 4);
      __syncthreads();
    }
  }
  // OUT = H*H -> global fp32
  {
    f32x16 acc = zero16();
    mac3<2>(acc, U1, U1 + PL, U1, U1 + PL, ln31, ln31, half);
    float* og = out + (size_t)blockIdx.x * 1024;
#pragma unroll
    for (int r = 0; r < 16; ++r) {
      if (r < 4 * wv || r >= 4 * wv + 4) continue;
      int rl = (r & 3) + 8 * (r >> 2) + 4 * half;
      og[rl * 32 + ln31] = acc[r];
    }
  }
}

extern "C" void kernel_launch(void* const* d_in, const int* in_sizes, int n_in,
                              void* d_out, int out_size, void* d_ws, size_t ws_size,
                              hipStream_t stream) {
  const float* X = (const float*)d_in[0];
  float* out = (float*)d_out;
  const int batch = in_sizes[0] / 4096;  // 8192
  spd_pool_kernel<<<batch, 256, 0, stream>>>(X, out);
}

// Round 5
// 580.661 us; speedup vs baseline: 5.2329x; 1.1569x over previous
//
#include <hip/hip_runtime.h>

typedef __attribute__((ext_vector_type(8))) short short8;
typedef __attribute__((ext_vector_type(4))) short short4v;
typedef __attribute__((ext_vector_type(16))) float f32x16;

#define PL 8256    // lo-plane offset: 8192 + 64B pad (bank shift by 16)
#define SLOT 16448 // hi(8192) + pad(64) + lo(8192)

__device__ __forceinline__ int swadr(int m, int kc) {
  return m * 128 + ((kc ^ (m & 7)) << 4);
}

__device__ __forceinline__ f32x16 zero16() {
  f32x16 z;
#pragma unroll
  for (int i = 0; i < 16; ++i) z[i] = 0.f;
  return z;
}

__device__ __forceinline__ unsigned short rne16(float v) {
  unsigned int u = __float_as_uint(v);
  return (unsigned short)((u + 0x7FFFu + ((u >> 16) & 1)) >> 16);
}
__device__ __forceinline__ float q16(float v) {  // round to bf16 value
  return __uint_as_float(((unsigned int)rne16(v)) << 16);
}

__device__ __forceinline__ void split_store8(char* slot, int byteoff, const float* v) {
  short8 h, l;
#pragma unroll
  for (int i = 0; i < 8; ++i) {
    unsigned int u = __float_as_uint(v[i]);
    h[i] = (short)(u >> 16);
    float hf = __uint_as_float(u & 0xFFFF0000u);
    l[i] = (short)(__float_as_uint(v[i] - hf) >> 16);
  }
  *(short8*)(slot + byteoff) = h;
  *(short8*)(slot + PL + byteoff) = l;
}

__device__ __forceinline__ void split_store4(char* slot, int byteoff, const float* v) {
  short4v h, l;
#pragma unroll
  for (int i = 0; i < 4; ++i) {
    unsigned int u = __float_as_uint(v[i]);
    h[i] = (short)(u >> 16);
    float hf = __uint_as_float(u & 0xFFFF0000u);
    l[i] = (short)(__float_as_uint(v[i] - hf) >> 16);
  }
  *(short4v*)(slot + byteoff) = h;
  *(short4v*)(slot + PL + byteoff) = l;
}

__device__ __forceinline__ void store_hi8(char* plane, int byteoff, const float* v) {
  short8 h;
#pragma unroll
  for (int i = 0; i < 8; ++i) h[i] = (short)rne16(v[i]);
  *(short8*)(plane + byteoff) = h;
}

// ---- MFMA macs (B symmetric -> row-read). acc is in/out (preloadable). ----
template <int NK>
__device__ __forceinline__ void mac1(f32x16& acc, const char* Ah, const char* Bh,
                                     int mA, int mB, int half) {
  const int baseA = mA * 128, maskA = mA & 7;
  const int baseB = mB * 128, maskB = mB & 7;
#pragma unroll
  for (int s = 0; s < NK; ++s) {
    int kc = 2 * s + half;
    short8 a = *(const short8*)(Ah + baseA + ((kc ^ maskA) << 4));
    short8 b = *(const short8*)(Bh + baseB + ((kc ^ maskB) << 4));
    acc = __builtin_amdgcn_mfma_f32_32x32x16_bf16(a, b, acc, 0, 0, 0);
  }
}

template <int NK>  // A split, B bf16
__device__ __forceinline__ void mac2A(f32x16& acc, const char* Ah, const char* Al,
                                      const char* Bh, int mA, int mB, int half) {
  const int baseA = mA * 128, maskA = mA & 7;
  const int baseB = mB * 128, maskB = mB & 7;
#pragma unroll
  for (int s = 0; s < NK; ++s) {
    int kc = 2 * s + half;
    int oA = baseA + ((kc ^ maskA) << 4);
    short8 ah = *(const short8*)(Ah + oA);
    short8 al = *(const short8*)(Al + oA);
    short8 b = *(const short8*)(Bh + baseB + ((kc ^ maskB) << 4));
    acc = __builtin_amdgcn_mfma_f32_32x32x16_bf16(ah, b, acc, 0, 0, 0);
    acc = __builtin_amdgcn_mfma_f32_32x32x16_bf16(al, b, acc, 0, 0, 0);
  }
}

template <int NK>  // A bf16, B split
__device__ __forceinline__ void mac2B(f32x16& acc, const char* Ah, const char* Bh,
                                      const char* Bl, int mA, int mB, int half) {
  const int baseA = mA * 128, maskA = mA & 7;
  const int baseB = mB * 128, maskB = mB & 7;
#pragma unroll
  for (int s = 0; s < NK; ++s) {
    int kc = 2 * s + half;
    int oB = baseB + ((kc ^ maskB) << 4);
    short8 a = *(const short8*)(Ah + baseA + ((kc ^ maskA) << 4));
    short8 bh = *(const short8*)(Bh + oB);
    short8 bl = *(const short8*)(Bl + oB);
    acc = __builtin_amdgcn_mfma_f32_32x32x16_bf16(a, bh, acc, 0, 0, 0);
    acc = __builtin_amdgcn_mfma_f32_32x32x16_bf16(a, bl, acc, 0, 0, 0);
  }
}

template <int NK>  // both split
__device__ __forceinline__ void mac3(f32x16& acc, const char* Ah, const char* Al,
                                     const char* Bh, const char* Bl,
                                     int mA, int mB, int half) {
  const int baseA = mA * 128, maskA = mA & 7;
  const int baseB = mB * 128, maskB = mB & 7;
#pragma unroll
  for (int s = 0; s < NK; ++s) {
    int kc = 2 * s + half;
    int oA = baseA + ((kc ^ maskA) << 4);
    int oB = baseB + ((kc ^ maskB) << 4);
    short8 ah = *(const short8*)(Ah + oA);
    short8 al = *(const short8*)(Al + oA);
    short8 bh = *(const short8*)(Bh + oB);
    short8 bl = *(const short8*)(Bl + oB);
    acc = __builtin_amdgcn_mfma_f32_32x32x16_bf16(ah, bh, acc, 0, 0, 0);
    acc = __builtin_amdgcn_mfma_f32_32x32x16_bf16(ah, bl, acc, 0, 0, 0);
    acc = __builtin_amdgcn_mfma_f32_32x32x16_bf16(al, bh, acc, 0, 0, 0);
  }
}

// split write of C-tile (both planes), DPP lane-pair packed b32
__device__ __forceinline__ void write_split(char* slot, int R, int C, int lane,
                                            const f32x16& vals, int r0, int r1) {
  const int ln31 = lane & 31;
  const bool ev = (ln31 & 1) == 0;
  const int col0 = C + (ln31 & ~1);
  const int cchunk = col0 >> 3;
  const int cbyte = (col0 & 7) * 2;
  const int rbase = R + 4 * (lane >> 5);
  const int pl = ev ? 0 : PL;
#pragma unroll
  for (int r = 0; r < 16; ++r) {
    if (r < r0 || r >= r1) continue;
    float v = vals[r];
    unsigned int u = __float_as_uint(v);
    unsigned int hu = u & 0xFFFF0000u;
    float lof = v - __uint_as_float(hu);
    unsigned int hs = hu >> 16;
    unsigned int ls = __float_as_uint(lof) >> 16;
    unsigned int hp = (unsigned int)__builtin_amdgcn_mov_dpp((int)hs, 0xB1, 0xF, 0xF, true);
    unsigned int lp = (unsigned int)__builtin_amdgcn_mov_dpp((int)ls, 0xB1, 0xF, 0xF, true);
    unsigned int word = ev ? (hs | (hp << 16)) : (lp | (ls << 16));
    int m = rbase + (r & 3) + 8 * (r >> 2);
    int off = m * 128 + ((cchunk ^ (m & 7)) << 4) + cbyte;
    *(unsigned int*)(slot + pl + off) = word;
  }
}

// bf16 (RNE) C-tile write into one PLANE
__device__ __forceinline__ void write_hi(char* plane, int R, int C, int lane,
                                         const f32x16& vals) {
  const int ln31 = lane & 31;
  const bool ev = (ln31 & 1) == 0;
  const int col0 = C + (ln31 & ~1);
  const int cchunk = col0 >> 3;
  const int cbyte = (col0 & 7) * 2;
  const int rbase = R + 4 * (lane >> 5);
#pragma unroll
  for (int r = 0; r < 16; ++r) {
    unsigned int hs = rne16(vals[r]);
    unsigned int hp = (unsigned int)__builtin_amdgcn_mov_dpp((int)hs, 0xB1, 0xF, 0xF, true);
    if (ev) {
      int m = rbase + (r & 3) + 8 * (r >> 2);
      *(unsigned int*)(plane + m * 128 + ((cchunk ^ (m & 7)) << 4) + cbyte) =
          hs | (hp << 16);
    }
  }
}

__global__ void __launch_bounds__(256, 3)
spd_pool_kernel(const float* __restrict__ X, float* __restrict__ out) {
  __shared__ __align__(16) char lds[3 * SLOT];
  char* U0 = lds;
  char* U1 = lds + SLOT;
  char* U2 = lds + 2 * SLOT;

  const int tid = threadIdx.x;
  const int lane = tid & 63;
  const int wv = tid >> 6;
  const int R = (wv >> 1) * 32;
  const int Cc = (wv & 1) * 32;
  const int half = lane >> 5;
  const int ln31 = lane & 31;
  const int mA = R + ln31;
  const int mB = Cc + ln31;

  const int em = tid >> 2;
  const int ekc = (tid & 3) * 2;
  const int ec0 = ekc * 8;

  f32x16 mY, mZ;

#define ROWM(r) (R + ((r) & 3) + 8 * ((r) >> 2) + 4 * half)
#define DIAG(r) ((ROWM(r) == Cc + ln31) ? 1.f : 0.f)

  // ======= init: U0 = X' = X/6.6 (split); U1h = Zh = T0 =======
  {
    const float ic1 = 1.0f / 6.6f;
    const float* Xg = X + (size_t)blockIdx.x * 4096 + em * 64 + ec0;
    const float4* xp = (const float4*)Xg;
    float4 a = xp[0], b = xp[1], c = xp[2], d = xp[3];
    float v[16] = {a.x * ic1, a.y * ic1, a.z * ic1, a.w * ic1,
                   b.x * ic1, b.y * ic1, b.z * ic1, b.w * ic1,
                   c.x * ic1, c.y * ic1, c.z * ic1, c.w * ic1,
                   d.x * ic1, d.y * ic1, d.z * ic1, d.w * ic1};
    float t[16];
#pragma unroll
    for (int i = 0; i < 16; ++i)
      t[i] = ((em == ec0 + i) ? 1.5f : 0.f) - 0.5f * v[i];
    split_store8(U0, swadr(em, ekc), v);
    split_store8(U0, swadr(em, ekc + 1), v + 8);
    store_hi8(U1, swadr(em, ekc), t);
    store_hi8(U1, swadr(em, ekc + 1), t + 8);
  }
  __syncthreads();
  // L1 iter1: Y = X'h * T0 -> U2h
  mY = zero16();
  mac1<4>(mY, U0, U1, mA, mB, half);
  write_hi(U2, R, Cc, lane, mY);
  __syncthreads();
  // L1 bf16 iters 2..5  (Y=U2h, Z=U1h, T=U2l)
#pragma unroll 1
  for (int it = 0; it < 4; ++it) {
    f32x16 a = zero16();
    mac1<4>(a, U1, U2, mA, mB, half);
    f32x16 tv;
#pragma unroll
    for (int r = 0; r < 16; ++r) tv[r] = 1.5f * DIAG(r) - 0.5f * a[r];
    write_hi(U2 + PL, R, Cc, lane, tv);
    __syncthreads();
    mY = zero16(); mac1<4>(mY, U2, U2 + PL, mA, mB, half);
    mZ = zero16(); mac1<4>(mZ, U2 + PL, U1, mA, mB, half);
    __syncthreads();
    write_hi(U2, R, Cc, lane, mY);
    write_hi(U1, R, Cc, lane, mZ);
    __syncthreads();
  }
  // L1 restore: mZ := bf16(mZ) (== U1h); mY = X' * Zh -> split U2
#pragma unroll
  for (int r = 0; r < 16; ++r) mZ[r] = q16(mZ[r]);
  mY = zero16();
  mac2A<4>(mY, U0, U0 + PL, U1, mA, mB, half);
  write_split(U2, R, Cc, lane, mY, 0, 16);
  __syncthreads();
  // L1 delta iter (Y only): D = 0.5(I - Zh*Y) -> U0h
  {
    f32x16 a = zero16();
    mac2B<4>(a, U1, U2, U2 + PL, mA, mB, half);
    f32x16 dv;
#pragma unroll
    for (int r = 0; r < 16; ++r) dv[r] = 0.5f * (DIAG(r) - a[r]);
    write_hi(U0, R, Cc, lane, dv);
  }
  __syncthreads();
  mac1<4>(mY, U2, U0, mA, mB, half);  // mY += Yh*D
  __syncthreads();
  write_split(U2, R, Cc, lane, mY, 0, 16);  // X2' = Y1 (split)
  // L2 T0 from mY (regs)
  {
    f32x16 t0v;
#pragma unroll
    for (int r = 0; r < 16; ++r) t0v[r] = 1.5f * DIAG(r) - 0.5f * mY[r];
    write_hi(U1, R, Cc, lane, t0v);  // Zh = T0
  }
  __syncthreads();
  // L2 iter1: Y = X2'h * T0 -> U0h
  mY = zero16();
  mac1<4>(mY, U2, U1, mA, mB, half);
  write_hi(U0, R, Cc, lane, mY);
  __syncthreads();
  // L2 bf16 iters 2..3 (Y=U0h, Z=U1h, T=U0l)
#pragma unroll 1
  for (int it = 0; it < 2; ++it) {
    f32x16 a = zero16();
    mac1<4>(a, U1, U0, mA, mB, half);
    f32x16 tv;
#pragma unroll
    for (int r = 0; r < 16; ++r) tv[r] = 1.5f * DIAG(r) - 0.5f * a[r];
    write_hi(U0 + PL, R, Cc, lane, tv);
    __syncthreads();
    mY = zero16(); mac1<4>(mY, U0, U0 + PL, mA, mB, half);
    mZ = zero16(); mac1<4>(mZ, U0 + PL, U1, mA, mB, half);
    __syncthreads();
    write_hi(U0, R, Cc, lane, mY);
    write_hi(U1, R, Cc, lane, mZ);
    __syncthreads();
  }
  // L2 restore
#pragma unroll
  for (int r = 0; r < 16; ++r) mZ[r] = q16(mZ[r]);
  mY = zero16();
  mac2A<4>(mY, U2, U2 + PL, U1, mA, mB, half);
  write_split(U0, R, Cc, lane, mY, 0, 16);
  __syncthreads();
  // L2 delta4
  {
    f32x16 a = zero16();
    mac2B<4>(a, U1, U0, U0 + PL, mA, mB, half);
    f32x16 dv;
#pragma unroll
    for (int r = 0; r < 16; ++r) dv[r] = 0.5f * (DIAG(r) - a[r]);
    write_hi(U2, R, Cc, lane, dv);  // D (X2' dead)
  }
  __syncthreads();
  mac1<4>(mY, U0, U2, mA, mB, half);  // mY += Yh*D
  mac1<4>(mZ, U2, U1, mA, mB, half);  // mZ += D*Zh
  __syncthreads();
  write_split(U0, R, Cc, lane, mY, 0, 16);
#pragma unroll
  for (int r = 0; r < 16; ++r) mZ[r] = q16(mZ[r]);
  write_hi(U1, R, Cc, lane, mZ);
  __syncthreads();
  // L2 delta5 (masters final, no writeback)
  {
    f32x16 a = zero16();
    mac2B<4>(a, U1, U0, U0 + PL, mA, mB, half);
    f32x16 dv;
#pragma unroll
    for (int r = 0; r < 16; ++r) dv[r] = 0.5f * (DIAG(r) - a[r]);
    write_hi(U2, R, Cc, lane, dv);
  }
  __syncthreads();
  mac1<4>(mY, U0, U2, mA, mB, half);
  mac1<4>(mZ, U2, U1, mA, mB, half);
  // S = ca*Y2 - cb*Z2 (regs) -> split U0
  f32x16 sv;
  {
    const float ca = 0.80141224f;  // 6.6^{1/4}/2
    const float cb = 0.31194493f;  // 1/(2*6.6^{1/4})
#pragma unroll
    for (int r = 0; r < 16; ++r) sv[r] = ca * mY[r] - cb * mZ[r];
  }
  __syncthreads();
  write_split(U0, R, Cc, lane, sv, 0, 16);
  __syncthreads();
  // S2 = S*S (masters); S2h -> U1h; q init -> U1l
  {
    f32x16 s2 = zero16();
    mac3<4>(s2, U0, U0 + PL, U0, U0 + PL, mA, mB, half);
    f32x16 qv;
    const float A11 = -0.08948864f, A9 = 0.12152778f;
#pragma unroll
    for (int r = 0; r < 16; ++r) qv[r] = A11 * s2[r] + A9 * DIAG(r);
    write_hi(U1, R, Cc, lane, s2);
    write_hi(U1 + PL, R, Cc, lane, qv);
  }
  __syncthreads();
  // asinh Horner (bf16): 3 steps
  {
    const float acoef[3] = {-0.17857143f, 0.3f, -0.66666667f};
#pragma unroll 1
    for (int j = 0; j < 3; ++j) {
      f32x16 a = zero16();
      mac1<4>(a, U1 + PL, U1, mA, mB, half);
      f32x16 tv;
#pragma unroll
      for (int r = 0; r < 16; ++r) tv[r] = a[r] + acoef[j] * DIAG(r);
      __syncthreads();
      write_hi(U1 + PL, R, Cc, lane, tv);
      __syncthreads();
    }
  }
  // last q step: q4 = q*S2 + 4I -> split U2
  {
    f32x16 a = zero16();
    mac1<4>(a, U1 + PL, U1, mA, mB, half);
    f32x16 tv;
#pragma unroll
    for (int r = 0; r < 16; ++r) tv[r] = a[r] + 4.f * DIAG(r);
    __syncthreads();
    write_split(U2, R, Cc, lane, tv, 0, 16);
    __syncthreads();
  }
  // L = S*q4 -> raw f32 into U1 region (row-major, 64x64)
  {
    f32x16 mL = zero16();
    mac3<4>(mL, U0, U0 + PL, U2, U2 + PL, mA, mB, half);
    float* Lf = (float*)U1;
#pragma unroll
    for (int r = 0; r < 16; ++r) Lf[ROWM(r) * 64 + Cc + ln31] = mL[r];
  }
  __syncthreads();
  // pool -> P2 = P/2 (split, U0 rows 0..31); q2 init -> U2
  {
    const float d8 = 2.4801587e-5f, d7 = 1.9841270e-4f;
    const float* Lf = (const float*)U1;
    int i = tid >> 3, ct = tid & 7, j4 = ct * 4;
    const float4* r0p = (const float4*)&Lf[(2 * i) * 64 + 8 * ct];
    const float4* r1p = (const float4*)&Lf[(2 * i + 1) * 64 + 8 * ct];
    float4 a0 = r0p[0], a1 = r0p[1], b0 = r1p[0], b1 = r1p[1];
    float p[4], q2v[4];
    p[0] = 0.125f * (a0.x + a0.y + b0.x + b0.y);
    p[1] = 0.125f * (a0.z + a0.w + b0.z + b0.w);
    p[2] = 0.125f * (a1.x + a1.y + b1.x + b1.y);
    p[3] = 0.125f * (a1.z + a1.w + b1.z + b1.w);
#pragma unroll
    for (int qq = 0; qq < 4; ++qq)
      q2v[qq] = d8 * p[qq] + ((i == j4 + qq) ? d7 : 0.f);
    int boff = swadr(i, ct >> 1) + (j4 & 7) * 2;
    split_store4(U0, boff, p);
    split_store4(U2, boff, q2v);
  }
  __syncthreads();
  // exp(P/2) Horner: 7 in-place steps on U2 (32x32)
  {
    const float dcoef[7] = {1.f / 720.f, 1.f / 120.f, 1.f / 24.f,
                            1.f / 6.f,   0.5f,        1.f,       1.f};
#pragma unroll 1
    for (int j = 0; j < 7; ++j) {
      f32x16 acc = zero16();
      mac3<2>(acc, U2, U2 + PL, U0, U0 + PL, ln31, ln31, half);
      f32x16 tv;
#pragma unroll
      for (int r = 0; r < 16; ++r) {
        int rl = (r & 3) + 8 * (r >> 2) + 4 * half;
        tv[r] = acc[r] + ((rl == ln31) ? dcoef[j] : 0.f);
      }
      __syncthreads();
      write_split(U2, 0, 0, lane, tv, 4 * wv, 4 * wv + 4);
      __syncthreads();
    }
  }
  // OUT = H*H -> global fp32
  {
    f32x16 acc = zero16();
    mac3<2>(acc, U2, U2 + PL, U2, U2 + PL, ln31, ln31, half);
    float* og = out + (size_t)blockIdx.x * 1024;
#pragma unroll
    for (int r = 0; r < 16; ++r) {
      if (r < 4 * wv || r >= 4 * wv + 4) continue;
      int rl = (r & 3) + 8 * (r >> 2) + 4 * half;
      og[rl * 32 + ln31] = acc[r];
    }
  }
#undef ROWM
#undef DIAG
}

extern "C" void kernel_launch(void* const* d_in, const int* in_sizes, int n_in,
                              void* d_out, int out_size, void* d_ws, size_t ws_size,
                              hipStream_t stream) {
  const float* X = (const float*)d_in[0];
  float* out = (float*)d_out;
  const int batch = in_sizes[0] / 4096;  // 8192
  spd_pool_kernel<<<batch, 256, 0, stream>>>(X, out);
}